// Round 5
// baseline (228.374 us; speedup 1.0000x reference)
//
#include <hip/hip_runtime.h>
#include <hip/hip_bf16.h>

// ws layout (floats):
//   [128..202]       quantized w_conv (75)
//   [256..44159]     quantized w_fc1 TRANSPOSED [j=343][o=128]
//   [44160..44671]   quantized w_fc2 [4][128]
#define WS_WCONV   128
#define WS_W1T     256
#define WS_W2      44160

__device__ __forceinline__ float q4(float w, float s) {
  if (s <= 0.f) return 0.f;
  float r = rintf(w / s);                     // round-half-even == jnp.round
  r = fminf(fmaxf(r, -8.f), 7.f);
  return r * s;
}

// Single quant dispatch (R3/R4-proven, absmax 0).
__global__ __launch_bounds__(256) void quant_all(
    const float* __restrict__ wconv, const float* __restrict__ w1,
    const float* __restrict__ w2, float* __restrict__ ws) {
  __shared__ float red[256];
  int b = blockIdx.x, t = threadIdx.x;
  if (b < 88) {
    const float4* w4 = (const float4*)w1;     // 43904/4 == 10976
    float m = 0.f;
    for (int i = t; i < 10976; i += 256) {
      float4 v = w4[i];
      m = fmaxf(m, fmaxf(fmaxf(fabsf(v.x), fabsf(v.y)),
                         fmaxf(fabsf(v.z), fabsf(v.w))));
    }
    red[t] = m;
    __syncthreads();
    for (int s = 128; s > 0; s >>= 1) {
      if (t < s) red[t] = fmaxf(red[t], red[t + s]);
      __syncthreads();
    }
    float s = red[0] * (1.0f / 7.0f);
    #pragma unroll
    for (int k = 0; k < 2; ++k) {
      int idx = b * 512 + k * 256 + t;
      if (idx < 43904) {
        float q = q4(w1[idx], s);
        int o = idx / 343;
        int j = idx - o * 343;
        ws[WS_W1T + j * 128 + o] = q;         // transpose for coalesced FC1
      }
    }
  } else {
    float mc = (t < 75) ? fabsf(wconv[t]) : 0.f;
    float m2 = 0.f;
    for (int i = t; i < 512; i += 256) m2 = fmaxf(m2, fabsf(w2[i]));
    red[t] = mc;
    __syncthreads();
    for (int s = 128; s > 0; s >>= 1) {
      if (t < s) red[t] = fmaxf(red[t], red[t + s]);
      __syncthreads();
    }
    float sc = red[0] * (1.0f / 7.0f);
    __syncthreads();
    red[t] = m2;
    __syncthreads();
    for (int s = 128; s > 0; s >>= 1) {
      if (t < s) red[t] = fmaxf(red[t], red[t + s]);
      __syncthreads();
    }
    float s2 = red[0] * (1.0f / 7.0f);
    if (t < 75) ws[WS_WCONV + t] = q4(wconv[t], sc);
    #pragma unroll
    for (int k = 0; k < 2; ++k) {
      int idx = k * 256 + t;
      ws[WS_W2 + idx] = q4(w2[idx], s2);
    }
  }
}

// LDS x layout: [d_local][h 0..15][quad-swizzled 32 floats].
// word = d*512 + h*32 + 4*(quad ^ (h&7)) + (w&3). Row base pw*4 is 16B
// aligned -> conv reads rows as 2x ds_read_b128; the XOR kills the
// stride-32 7-way ph bank-aliasing down to <=2-way (free, m136).
__device__ __forceinline__ void stage_chunk(
    const float* __restrict__ x, int b, int d0, int ndep,
    float* __restrict__ xs, int t) {
  int ntask = ndep * 16 * 8;                  // (d,h) rows x 8 quads
  for (int i = t; i < ntask; i += 256) {
    int r = i >> 3, q = i & 7;
    int d = r >> 4, h = r & 15;
    const float* g = x + (size_t)b * 15376 + (d0 + d) * 496 + h * 31 + 4 * q;
    float v0 = g[0], v1 = g[1], v2 = g[2];
    float v3 = (q < 7) ? g[3] : 0.f;          // pad word w=31
    int dst = d * 512 + h * 32 + ((q ^ (h & 7)) << 2);
    *(float4*)&xs[dst] = make_float4(v0, v1, v2, v3);
  }
}

// Conv phase: npf threads, pd = pd_off + t/49; chunk holds local depths
// d_global - 4*pd_off0 (chunk A: d0=0; chunk B: d0=12 -> pdl = pd-3).
__device__ __forceinline__ void conv_phase(
    const float* __restrict__ xs, const float* __restrict__ wq,
    int t, int npf, int pd_off, float bc, float* __restrict__ feat) {
  if (t >= npf) return;
  int pdl = t / 49;
  int rr  = t - pdl * 49;
  int ph  = rr / 7;
  int pw  = rr - ph * 7;
  float c[2][2][2];
  #pragma unroll
  for (int i = 0; i < 8; ++i) ((float*)c)[i] = 0.f;
  #pragma unroll
  for (int dd = 0; dd < 7; ++dd) {
    int dbase = (4 * pdl + dd) * 512;
    #pragma unroll
    for (int hh = 0; hh < 4; ++hh) {
      int h = 2 * ph + hh;
      int hb = h & 7;
      int base = dbase + h * 32;
      float4 ra = *(const float4*)&xs[base + (((pw)     ^ hb) << 2)];
      float4 rb = *(const float4*)&xs[base + (((pw + 1) ^ hb) << 2)];
      float row[8] = {ra.x, ra.y, ra.z, ra.w, rb.x, rb.y, rb.z, rb.w};
      #pragma unroll
      for (int odp = 0; odp < 2; ++odp) {
        int kd = dd - 2 * odp;
        if (kd < 0 || kd > 4) continue;       // folds at compile time
        #pragma unroll
        for (int ohp = 0; ohp < 2; ++ohp) {
          int kh = hh - ohp;
          if (kh < 0 || kh > 2) continue;     // folds at compile time
          #pragma unroll
          for (int owp = 0; owp < 2; ++owp) {
            float a = c[odp][ohp][owp];
            #pragma unroll
            for (int kw = 0; kw < 5; ++kw)
              a = fmaf(row[2 * owp + kw], wq[kd * 15 + kh * 5 + kw], a);
            c[odp][ohp][owp] = a;
          }
        }
      }
    }
  }
  float m = ((float*)c)[0];
  #pragma unroll
  for (int i = 1; i < 8; ++i) m = fmaxf(m, ((float*)c)[i]);
  feat[(pdl + pd_off) * 49 + rr] = m + bc;
}

// Fused net: chunk A (d 0..14, pd 0..2) -> chunk B (d 12..30, pd 3..6) ->
// FC1 -> FC2 -> softmax. xs 38,912B + feat 1376B = 40.3KB -> 4 blocks/CU
// (fc1p/a1/s2 alias xs after conv).
__global__ __launch_bounds__(256, 4) void fused_net(
    const float* __restrict__ x, const float* __restrict__ bconv,
    const float* __restrict__ ws, const float* __restrict__ bfc1,
    const float* __restrict__ bfc2, float* __restrict__ out) {
  __shared__ float xs[9728];                  // 19 depths * 512
  __shared__ float feat[344];                 // +1: feat[343]=0 pads FC1 quads
  float* fc1p = xs;                           // alias: used only after conv
  float* a1   = xs + 128;
  float* s2   = xs + 256;
  int t = threadIdx.x;
  int b = blockIdx.x;
  const float* wq = ws + WS_WCONV;
  float bc = bconv[0];

  if (t == 0) feat[343] = 0.f;
  // P1: stage depths 0..14
  stage_chunk(x, b, 0, 15, xs, t);
  __syncthreads();
  // P2: conv pd 0..2 (147 threads)
  conv_phase(xs, wq, t, 147, 0, bc, feat);
  __syncthreads();
  // P3: stage depths 12..30
  stage_chunk(x, b, 12, 19, xs, t);
  __syncthreads();
  // P4: conv pd 3..6 (196 threads)
  conv_phase(xs, wq, t, 196, 3, bc, feat);
  __syncthreads();

  // P5: FC1 (343->128): g = j-half, o = output. feat read as b128 quads
  // (broadcast, conflict-free); w1T global lane-coalesced. g=1 tail quad
  // uses feat[343]=0 (w1T row 343 lands in finite W2 region * 0.0 -> exact).
  int g = t >> 7, o = t & 127;
  {
    const float* w1T = ws + WS_W1T;
    int j0 = g ? 172 : 0;
    const float4* f4 = (const float4*)&feat[j0];
    const float* wp = w1T + j0 * 128 + o;
    float p0 = 0.f, p1 = 0.f, p2 = 0.f, p3 = 0.f;
    for (int q = 0; q < 43; ++q) {
      float4 ff = f4[q];
      p0 = fmaf(ff.x, wp[0],   p0);
      p1 = fmaf(ff.y, wp[128], p1);
      p2 = fmaf(ff.z, wp[256], p2);
      p3 = fmaf(ff.w, wp[384], p3);
      wp += 512;
    }
    float acc = (p0 + p1) + (p2 + p3);
    if (g) fc1p[o] = acc;
    __syncthreads();
    if (!g) a1[o] = fmaxf(acc + fc1p[o] + bfc1[o], 0.f);
  }
  __syncthreads();

  // P6: FC2 (128->4) on one wave: lane = (kk,cls), shuffle-reduce over kk.
  if (t < 64) {
    int cls = t & 3, kk = t >> 2;             // kk 0..15, 8 k's each
    const float* w2 = ws + WS_W2 + cls * 128 + kk * 8;
    const float* av = a1 + kk * 8;
    float p = 0.f;
    #pragma unroll
    for (int i = 0; i < 8; ++i) p = fmaf(av[i], w2[i], p);
    p += __shfl_down(p, 32);
    p += __shfl_down(p, 16);
    p += __shfl_down(p, 8);
    p += __shfl_down(p, 4);
    if (t < 4) s2[t] = p + bfc2[t];
  }
  __syncthreads();
  // P7: softmax + store
  if (t < 4) {
    float v0 = s2[0], v1 = s2[1], v2 = s2[2], v3 = s2[3];
    float m = fmaxf(fmaxf(v0, v1), fmaxf(v2, v3));
    float e0 = expf(v0 - m), e1 = expf(v1 - m);
    float e2 = expf(v2 - m), e3 = expf(v3 - m);
    float inv = 1.f / (e0 + e1 + e2 + e3);
    float mine = (t == 0) ? e0 : (t == 1) ? e1 : (t == 2) ? e2 : e3;
    out[b * 4 + t] = mine * inv;
  }
}

extern "C" void kernel_launch(void* const* d_in, const int* in_sizes, int n_in,
                              void* d_out, int out_size, void* d_ws, size_t ws_size,
                              hipStream_t stream) {
  const float* x     = (const float*)d_in[0];
  const float* wconv = (const float*)d_in[1];
  const float* bconv = (const float*)d_in[2];
  const float* wfc1  = (const float*)d_in[3];
  const float* bfc1  = (const float*)d_in[4];
  const float* wfc2  = (const float*)d_in[5];
  const float* bfc2  = (const float*)d_in[6];
  float* out = (float*)d_out;
  float* ws  = (float*)d_ws;

  quant_all<<<89, 256, 0, stream>>>(wconv, wfc1, wfc2, ws);
  fused_net<<<2048, 256, 0, stream>>>(x, bconv, ws, bfc1, bfc2, out);
}